// Round 26
// baseline (93.197 us; speedup 1.0000x reference)
//
#include <hip/hip_runtime.h>

typedef unsigned short u16;
typedef short s16x4 __attribute__((ext_vector_type(4)));
typedef short short8 __attribute__((ext_vector_type(8)));
typedef __bf16 bf16x8 __attribute__((ext_vector_type(8)));
typedef float f32x4 __attribute__((ext_vector_type(4)));
typedef float f32x2 __attribute__((ext_vector_type(2)));
typedef float f32x16 __attribute__((ext_vector_type(16)));

#define DEV static __device__ __forceinline__

DEV u16 f2b(float f){
  union { float f; unsigned u; } v; v.f = f;
  return (u16)((v.u + 0x7fffu + ((v.u >> 16) & 1u)) >> 16);
}

DEV float b2f(u16 u){
  union { unsigned u; float f; } v; v.u = ((unsigned)u) << 16; return v.f;
}

DEV f32x4 mfma16(short8 a, short8 b, f32x4 c){
  return __builtin_amdgcn_mfma_f32_16x16x32_bf16(
      __builtin_bit_cast(bf16x8, a), __builtin_bit_cast(bf16x8, b), c, 0, 0, 0);
}

DEV f32x16 mfma32(short8 a, short8 b, f32x16 c){
  return __builtin_amdgcn_mfma_f32_32x32x16_bf16(
      __builtin_bit_cast(bf16x8, a), __builtin_bit_cast(bf16x8, b), c, 0, 0, 0);
}

DEV short8 ld8(const u16* p){ return *(const short8*)p; }

#if __has_builtin(__builtin_amdgcn_exp2f)
DEV float fexp2(float x){ return __builtin_amdgcn_exp2f(x); }
#else
DEV float fexp2(float x){ return exp2f(x); }
#endif

#define LOG2E 1.44269504088896341f

// ---------------- weight convert + transpose (fp32 -> bf16, [out_col][k]) + h -> bf16 (vec) -------
struct WConvArgs { const float* w[12]; const float* w1; const float* w2; const float* h; u16* dst; u16* hb; };
__global__ __launch_bounds__(256) void k_convert_w(WConvArgs a){
  int i = blockIdx.x*256 + threadIdx.x;
  if (i >= 458752) return;
  if (i >= 327680){
    int j = (i - 327680) << 3;          // 8 h elements per thread, coalesced
    f32x4 v0 = *(const f32x4*)(a.h + j);
    f32x4 v1 = *(const f32x4*)(a.h + j + 4);
    short8 o;
    #pragma unroll
    for (int t = 0; t < 4; ++t){ o[t] = (short)f2b(v0[t]); o[4+t] = (short)f2b(v1[t]); }
    *(short8*)(a.hb + j) = o;
    return;
  }
  float v;
  if (i < 196608){ int w = i >> 14, rem = i & 16383, c = rem >> 7, k = rem & 127; v = a.w[w][k*128 + c]; }
  else if (i < 262144){ int rem = i - 196608, c = rem >> 7, k = rem & 127; v = a.w1[k*512 + c]; }
  else { int rem = i - 262144, c = rem >> 9, k = rem & 511; v = a.w2[k*128 + c]; }
  a.dst[i] = f2b(v);
}

// ---------------- fused QKV projections (9 GEMMs, X = h bf16), 32x64 out per wave ----------------
// V output layout: [B, H, blk=N/32, dh=16, pos=32] with pos = key permuted (bits 2<->3 of krel)
// so attention's 32x32x16 PV A-fragment reads are contiguous 16B/lane.
struct ProjDesc {
  const u16* Wt; const float* bias; u16* dst;
  int lg_rpb, row_off, vtrans, tile_end; float scale;
};
struct ProjArgs { ProjDesc d[9]; const u16* X; };
__global__ __launch_bounds__(256) void k_qkv(ProjArgs A){
  int wave = (blockIdx.x << 2) + (threadIdx.x >> 6);
  int lane = threadIdx.x & 63;
  int j = 0, base = 0;
  #pragma unroll
  for (int t = 0; t < 8; ++t)
    if (wave >= A.d[t].tile_end){ j = t + 1; base = A.d[t].tile_end; }
  ProjDesc d = A.d[j];
  int local = wave - base;
  int ch = local & 1, rt = local >> 1;
  int lrow = lane & 15, lgrp = lane >> 4, kb = lgrp << 3;
  int rpb_m1 = (1 << d.lg_rpb) - 1;
  int nq = rpb_m1 + 1;
  int rA = (rt << 5) + lrow, rB = rA + 16;
  int gA = ((rA >> d.lg_rpb) << 11) + (rA & rpb_m1) + d.row_off;
  int gB = ((rB >> d.lg_rpb) << 11) + (rB & rpb_m1) + d.row_off;
  const u16* xpA = A.X + (size_t)gA*128 + kb;
  const u16* xpB = A.X + (size_t)gB*128 + kb;
  short8 aA0 = ld8(xpA), aA1 = ld8(xpA+32), aA2 = ld8(xpA+64), aA3 = ld8(xpA+96);
  short8 aB0 = ld8(xpB), aB1 = ld8(xpB+32), aB2 = ld8(xpB+64), aB3 = ld8(xpB+96);
  // constants for vtrans store
  int rr0base = rt << 5;
  int b_of = rr0base >> d.lg_rpb;            // block of 32 rows never crosses batch boundary
  int q0_ = rr0base & rpb_m1;
  int blk = q0_ >> 5;
  int lgrp2 = ((lgrp & 1) << 1) | (lgrp >> 1);   // swap the two bits (perm of key slots)
  #pragma unroll
  for (int cc = 0; cc < 4; ++cc){
    int c = (ch << 6) + (cc << 4) + lrow;
    const u16* wp = d.Wt + c*128 + kb;
    short8 w0 = ld8(wp), w1 = ld8(wp+32), w2 = ld8(wp+64), w3 = ld8(wp+96);
    f32x4 accA = {0.f,0.f,0.f,0.f}, accB = {0.f,0.f,0.f,0.f};
    accA = mfma16(aA0, w0, accA); accB = mfma16(aB0, w0, accB);
    accA = mfma16(aA1, w1, accA); accB = mfma16(aB1, w1, accB);
    accA = mfma16(aA2, w2, accA); accB = mfma16(aB2, w2, accB);
    accA = mfma16(aA3, w3, accA); accB = mfma16(aB3, w3, accB);
    float bv = d.bias[c];
    int hh = c >> 4, dd = c & 15;
    #pragma unroll
    for (int half = 0; half < 2; ++half){
      f32x4 acc = half ? accB : accA;
      if (d.vtrans){
        s16x4 ov;
        #pragma unroll
        for (int i = 0; i < 4; ++i) ov[i] = (short)f2b((acc[i] + bv) * d.scale);
        size_t off = ((size_t)((b_of*8 + hh)*(nq >> 5) + blk))*512 + dd*32 + half*16 + lgrp2*4;
        *(s16x4*)(d.dst + off) = ov;
      } else {
        #pragma unroll
        for (int i = 0; i < 4; ++i){
          int rr = (rt << 5) + half*16 + (lgrp << 2) + i;
          int b = rr >> d.lg_rpb, q = rr & rpb_m1;
          float val = (acc[i] + bv) * d.scale;
          size_t off = ((size_t)((b*8 + hh)*nq + q))*16 + dd;   // Q/K: [B,H,N,dh]
          d.dst[off] = f2b(val);
        }
      }
    }
  }
}

// ---------------- fused attention (3 attns, swapped-QK^T via 32x32x16, 32 q-rows/wave) ------
// 128 keys/iter as FOUR independent 32-key chains (quad accumulators) for max in-wave ILP.
// dh=16 == K of mfma_32x32x16. C/D layout: col=lane&31, row=(reg&3)+8*(reg>>2)+4*(lane>>5).
// V^T A-frag row 16 = ones -> PV row 16 = sum(P) = softmax denominator (free).
// Scores bounded (|s| << 1) -> no max subtraction. Q pre-scaled by 0.25*log2(e) -> exp2.
// XCD-aware block swizzle keeps each bh's K/V in one XCD's L2. Staggered key start per wave.
struct AttnDesc { const u16* Q; const u16* K; const u16* Vt; u16* ctx; int Nq, Nk, lg_nqt, wave_end; };
struct AttnArgs { AttnDesc d[3]; };
__global__ __launch_bounds__(256, 3) void k_attn(AttnArgs A){
  int wid = threadIdx.x >> 6, lane = threadIdx.x & 63;
  int p = blockIdx.x;
  int lb;
  if (p < 512){ lb = (p & 7)*64 + (p >> 3); }                       // sa: 8 xcd x 64 slots
  else if (p < 768){ int q = p - 512; lb = 512 + (q & 7)*32 + (q >> 3); }  // l2b
  else { int q = p - 768; lb = 768 + (q & 7)*32 + (q >> 3); }             // b2l
  int wave = (lb << 2) + wid;
  int j = 0, base = 0;
  #pragma unroll
  for (int t = 0; t < 2; ++t)
    if (wave >= A.d[t].wave_end){ j = t + 1; base = A.d[t].wave_end; }
  AttnDesc d = A.d[j];
  int local = wave - base;
  int bh = local >> d.lg_nqt;                  // lg_nqt = log2(#32-row q-tiles)
  int qt = local & ((1 << d.lg_nqt) - 1);
  int q0 = qt << 5;                            // 32 q-rows per wave
  int lq = lane & 31, hi = lane >> 5;
  const u16* Qb = d.Q + (size_t)bh * d.Nq * 16;
  const u16* Kb = d.K + (size_t)bh * d.Nk * 16;
  const u16* Vb = d.Vt + (size_t)bh * 16 * d.Nk;   // [blk][dh][pos32]
  short8 zs = {0,0,0,0,0,0,0,0};
  short8 ones = {0x3F80,0x3F80,0x3F80,0x3F80,0x3F80,0x3F80,0x3F80,0x3F80};
  short8 bq = ld8(Qb + (q0 + lq)*16 + hi*8);       // B-frag Q: col q=q0+lq
  const u16* kp0 = Kb + lq*16 + hi*8;              // A-frag K: row key=lq
  bool vload = lq < 16;
  bool vone  = lq == 16;
  const u16* vbase = Vb + (lq & 15)*32 + hi*8;
  f32x16 oA = {0.f,0.f,0.f,0.f,0.f,0.f,0.f,0.f,0.f,0.f,0.f,0.f,0.f,0.f,0.f,0.f};
  f32x16 oB = oA, oC = oA, oD = oA;
  f32x16 z16 = oA;
  int nt = d.Nk >> 7;                               // 128-key tiles (power of 2)
  int toff = wid * (nt >> 2);                       // stagger waves across key space
  for (int it = 0; it < nt; ++it){
    int k0 = ((it + toff) & (nt - 1)) << 7;
    const u16* kp = kp0 + k0*16;
    short8 aK0 = ld8(kp), aK1 = ld8(kp + 512), aK2 = ld8(kp + 1024), aK3 = ld8(kp + 1536);
    short8 v0a, v1a, v0b, v1b, v0c, v1c, v0d, v1d;
    if (vload){
      const u16* vp = vbase + (size_t)(k0 >> 5)*512;
      v0a = ld8(vp);         v1a = ld8(vp + 16);
      v0b = ld8(vp + 512);   v1b = ld8(vp + 528);
      v0c = ld8(vp + 1024);  v1c = ld8(vp + 1040);
      v0d = ld8(vp + 1536);  v1d = ld8(vp + 1552);
    } else if (vone){
      v0a = ones; v1a = ones; v0b = ones; v1b = ones;
      v0c = ones; v1c = ones; v0d = ones; v1d = ones;
    } else {
      v0a = zs; v1a = zs; v0b = zs; v1b = zs;
      v0c = zs; v1c = zs; v0d = zs; v1d = zs;
    }
    __builtin_amdgcn_s_setprio(1);
    f32x16 sA = mfma32(aK0, bq, z16);   // four independent QK MFMAs
    f32x16 sB = mfma32(aK1, bq, z16);
    f32x16 sC = mfma32(aK2, bq, z16);
    f32x16 sD = mfma32(aK3, bq, z16);
    __builtin_amdgcn_s_setprio(0);
    float pa[16], pb_[16], pc[16], pd[16];
    #pragma unroll
    for (int i = 0; i < 16; ++i){
      pa[i] = fexp2(sA[i]); pb_[i] = fexp2(sB[i]);
      pc[i] = fexp2(sC[i]); pd[i] = fexp2(sD[i]);
    }
    bf16x8 a0, a1, b0, b1, c0, c1, d0, d1;
    #pragma unroll
    for (int i = 0; i < 8; ++i){
      a0[i] = (__bf16)pa[i];  a1[i] = (__bf16)pa[8+i];
      b0[i] = (__bf16)pb_[i]; b1[i] = (__bf16)pb_[8+i];
      c0[i] = (__bf16)pc[i];  c1[i] = (__bf16)pc[8+i];
      d0[i] = (__bf16)pd[i];  d1[i] = (__bf16)pd[8+i];
    }
    __builtin_amdgcn_s_setprio(1);
    oA = mfma32(v0a, __builtin_bit_cast(short8, a0), oA);
    oB = mfma32(v0b, __builtin_bit_cast(short8, b0), oB);
    oC = mfma32(v0c, __builtin_bit_cast(short8, c0), oC);
    oD = mfma32(v0d, __builtin_bit_cast(short8, d0), oD);
    oA = mfma32(v1a, __builtin_bit_cast(short8, a1), oA);
    oB = mfma32(v1b, __builtin_bit_cast(short8, b1), oB);
    oC = mfma32(v1c, __builtin_bit_cast(short8, c1), oC);
    oD = mfma32(v1d, __builtin_bit_cast(short8, d1), oD);
    __builtin_amdgcn_s_setprio(0);
  }
  f32x16 o = (oA + oB) + (oC + oD);
  // denominator: D row 16 (reg 8, hi=0 lanes) = sum over all keys of P
  float l = o[8];
  l += __shfl_xor(l, 32);
  float invl = 1.f / l;
  int b = bh >> 3, h = bh & 7;
  u16* cb = d.ctx + ((size_t)(b*d.Nq + q0 + lq))*128 + h*16;
  s16x4 ov0, ov1;
  #pragma unroll
  for (int i = 0; i < 4; ++i){
    ov0[i] = (short)f2b(o[i]   * invl);       // regs 0-3: dv = i + 4*hi
    ov1[i] = (short)f2b(o[4+i] * invl);       // regs 4-7: dv = 8 + i + 4*hi
  }
  *(s16x4*)(cb + 4*hi)     = ov0;
  *(s16x4*)(cb + 8 + 4*hi) = ov1;
}

// ---------------- fused O projections + LN1: xb = bf16(LN1(h + ctx_sa@Wo_sa + ctx_het@Wo_het)) ----
// One wave per block (512 blocks -> 2 blocks/CU, all CUs busy), 16 rows x 128 cols, 64 MFMAs.
struct OProjArgs {
  const u16 *ctx_sa, *ctx_l, *ctx_b, *wo_sa, *wo_l, *wo_b;
  const float *bo_sa, *bo_l, *bo_b, *h, *gam, *bet;
  u16* xb;
};
__global__ __launch_bounds__(64) void k_oproj(OProjArgs A){
  int rt = blockIdx.x;                  // 512 blocks, 1 wave each
  int lane = threadIdx.x & 63;
  int lq = lane & 15, grp = lane >> 4, kb = grp << 3;
  int r0 = rt << 4;
  int r = r0 + lq;
  int b = r >> 11, q = r & 2047;
  bool lo = (q & 1024) == 0;
  int qh = q & 1023;
  const u16* asa = A.ctx_sa + (size_t)r*128 + kb;
  const u16* ah  = (lo ? A.ctx_l : A.ctx_b) + ((size_t)(b*1024 + qh))*128 + kb;
  short8 as0 = ld8(asa), as1 = ld8(asa+32), as2 = ld8(asa+64), as3 = ld8(asa+96);
  short8 ah0 = ld8(ah),  ah1 = ld8(ah+32),  ah2 = ld8(ah+64),  ah3 = ld8(ah+96);
  const u16* wlo = lo ? A.wo_l : A.wo_b;
  const float* blo = lo ? A.bo_l : A.bo_b;
  float v[8][4];                        // v[ct][i]: row r0+grp*4+i, col ct*16+lq
  #pragma unroll
  for (int ct = 0; ct < 8; ++ct){
    int c = (ct << 4) + lq;
    const u16* wsa = A.wo_sa + c*128 + kb;
    const u16* wh  = wlo + c*128 + kb;
    f32x4 acc = {0.f,0.f,0.f,0.f};
    acc = mfma16(as0, ld8(wsa),      acc);
    acc = mfma16(as1, ld8(wsa + 32), acc);
    acc = mfma16(as2, ld8(wsa + 64), acc);
    acc = mfma16(as3, ld8(wsa + 96), acc);
    acc = mfma16(ah0, ld8(wh),       acc);
    acc = mfma16(ah1, ld8(wh + 32),  acc);
    acc = mfma16(ah2, ld8(wh + 64),  acc);
    acc = mfma16(ah3, ld8(wh + 96),  acc);
    float bv = A.bo_sa[c] + blo[c];
    #pragma unroll
    for (int i = 0; i < 4; ++i){
      int rr = r0 + (grp << 2) + i;
      v[ct][i] = A.h[(size_t)rr*128 + c] + acc[i] + bv;
    }
  }
  // per-row LN over the 16 lanes of this group
  float s[4], sq[4];
  #pragma unroll
  for (int i = 0; i < 4; ++i){
    float a = 0.f, bb = 0.f;
    #pragma unroll
    for (int ct = 0; ct < 8; ++ct){ a += v[ct][i]; bb += v[ct][i]*v[ct][i]; }
    s[i] = a; sq[i] = bb;
  }
  #pragma unroll
  for (int dd = 1; dd < 16; dd <<= 1){
    #pragma unroll
    for (int i = 0; i < 4; ++i){ s[i] += __shfl_xor(s[i], dd); sq[i] += __shfl_xor(sq[i], dd); }
  }
  float mean[4], rstd[4];
  #pragma unroll
  for (int i = 0; i < 4; ++i){
    mean[i] = s[i] * 0.0078125f;
    rstd[i] = rsqrtf(fmaxf(sq[i]*0.0078125f - mean[i]*mean[i], 0.f) + 1e-5f);
  }
  #pragma unroll
  for (int ct = 0; ct < 8; ++ct){
    int c = (ct << 4) + lq;
    float g = A.gam[c], be = A.bet[c];
    #pragma unroll
    for (int i = 0; i < 4; ++i){
      int rr = r0 + (grp << 2) + i;
      A.xb[(size_t)rr*128 + c] = f2b((v[ct][i] - mean[i])*rstd[i]*g + be);
    }
  }
}

// ---------------- FF1 (pure GEMM): t = relu(xb @ W1 + b1), 32 rows x 64 cols per wave ----------
__global__ __launch_bounds__(256) void k_ff1(const u16* xb, const u16* w1t, const float* b1, u16* t){
  int wave = (blockIdx.x << 2) + (threadIdx.x >> 6);
  int lane = threadIdx.x & 63;
  int ch = wave & 7, rt = wave >> 3;
  int lrow = lane & 15, lgrp = lane >> 4, kb = lgrp << 3;
  int rA = (rt << 5) + lrow, rB = rA + 16;
  const u16* xpA = xb + (size_t)rA*128 + kb;
  const u16* xpB = xb + (size_t)rB*128 + kb;
  short8 aA0 = ld8(xpA), aA1 = ld8(xpA+32), aA2 = ld8(xpA+64), aA3 = ld8(xpA+96);
  short8 aB0 = ld8(xpB), aB1 = ld8(xpB+32), aB2 = ld8(xpB+64), aB3 = ld8(xpB+96);
  #pragma unroll
  for (int cc = 0; cc < 4; ++cc){
    int c = (ch << 6) + (cc << 4) + lrow;
    const u16* wp = w1t + c*128 + kb;
    short8 w0 = ld8(wp), w1 = ld8(wp+32), w2 = ld8(wp+64), w3 = ld8(wp+96);
    f32x4 accA = {0.f,0.f,0.f,0.f}, accB = {0.f,0.f,0.f,0.f};
    accA = mfma16(aA0, w0, accA); accB = mfma16(aB0, w0, accB);
    accA = mfma16(aA1, w1, accA); accB = mfma16(aB1, w1, accB);
    accA = mfma16(aA2, w2, accA); accB = mfma16(aB2, w2, accB);
    accA = mfma16(aA3, w3, accA); accB = mfma16(aB3, w3, accB);
    float bv = b1[c];
    #pragma unroll
    for (int half = 0; half < 2; ++half){
      f32x4 acc = half ? accB : accA;
      #pragma unroll
      for (int i = 0; i < 4; ++i){
        int rr = (rt << 5) + half*16 + (lgrp << 2) + i;
        t[(size_t)rr*512 + c] = f2b(fmaxf(acc[i] + bv, 0.f));
      }
    }
  }
}

// ---------------- FF2 + final LN fused: out = LN(xb + t @ W2 + b2)  ----------------
// One wave per 16 rows, full 128 cols (8 col-tiles, K=512 -> 128 MFMAs).
// After epilogue each 16-lane group holds complete rows -> in-register LN, write d_out.
__global__ __launch_bounds__(64) void k_ff2ln(const u16* t, const u16* w2t, const float* b2,
                                              const u16* xb, const float* gam, const float* bet,
                                              float* out){
  int rt = blockIdx.x;                 // 512 blocks, 1 wave each
  int lane = threadIdx.x & 63;
  int lq = lane & 15, grp = lane >> 4, kb = grp << 3;
  int r0 = rt << 4;
  const u16* ap = t + (size_t)(r0 + lq)*512 + kb;
  short8 af[16];
  #pragma unroll
  for (int ks = 0; ks < 16; ++ks) af[ks] = ld8(ap + ks*32);
  float v[8][4];                       // v[ct][i]: row r0+grp*4+i, col ct*16+lq
  #pragma unroll
  for (int ct = 0; ct < 8; ++ct){
    int c = (ct << 4) + lq;
    const u16* wp = w2t + (size_t)c*512 + kb;
    f32x4 acc = {0.f,0.f,0.f,0.f};
    #pragma unroll
    for (int ks = 0; ks < 16; ++ks) acc = mfma16(af[ks], ld8(wp + ks*32), acc);
    float bv = b2[c];
    #pragma unroll
    for (int i = 0; i < 4; ++i){
      int rr = r0 + (grp << 2) + i;
      v[ct][i] = b2f(xb[(size_t)rr*128 + c]) + acc[i] + bv;
    }
  }
  // per-row LN: row rr held by the 16 lanes of this grp (8 cols each)
  float s[4], sq[4];
  #pragma unroll
  for (int i = 0; i < 4; ++i){
    float a = 0.f, b = 0.f;
    #pragma unroll
    for (int ct = 0; ct < 8; ++ct){ a += v[ct][i]; b += v[ct][i]*v[ct][i]; }
    s[i] = a; sq[i] = b;
  }
  #pragma unroll
  for (int d = 1; d < 16; d <<= 1){
    #pragma unroll
    for (int i = 0; i < 4; ++i){ s[i] += __shfl_xor(s[i], d); sq[i] += __shfl_xor(sq[i], d); }
  }
  float mean[4], rstd[4];
  #pragma unroll
  for (int i = 0; i < 4; ++i){
    mean[i] = s[i] * 0.0078125f;
    rstd[i] = rsqrtf(fmaxf(sq[i]*0.0078125f - mean[i]*mean[i], 0.f) + 1e-5f);
  }
  #pragma unroll
  for (int ct = 0; ct < 8; ++ct){
    int c = (ct << 4) + lq;
    float g = gam[c], be = bet[c];
    #pragma unroll
    for (int i = 0; i < 4; ++i){
      int rr = r0 + (grp << 2) + i;
      out[(size_t)rr*128 + c] = (v[ct][i] - mean[i])*rstd[i]*g + be;
    }
  }
}

extern "C" void kernel_launch(void* const* d_in, const int* in_sizes, int n_in,
                              void* d_out, int out_size, void* d_ws, size_t ws_size,
                              hipStream_t stream){
  const float* h      = (const float*)d_in[0];
  const float* sa_wq  = (const float*)d_in[3];  const float* sa_bq  = (const float*)d_in[4];
  const float* sa_wk  = (const float*)d_in[5];  const float* sa_bk  = (const float*)d_in[6];
  const float* sa_wv  = (const float*)d_in[7];  const float* sa_bv  = (const float*)d_in[8];
  const float* sa_wo  = (const float*)d_in[9];  const float* sa_bo  = (const float*)d_in[10];
  const float* l2b_wq = (const float*)d_in[11]; const float* l2b_bq = (const float*)d_in[12];
  const float* l2b_wk = (const float*)d_in[13]; const float* l2b_bk = (const float*)d_in[14];
  const float* l2b_wv = (const float*)d_in[15]; const float* l2b_bv = (const float*)d_in[16];
  const float* l2b_wo = (const float*)d_in[17]; const float* l2b_bo = (const float*)d_in[18];
  const float* b2l_wq = (const float*)d_in[19]; const float* b2l_bq = (const float*)d_in[20];
  const float* b2l_wk = (const float*)d_in[21]; const float* b2l_bk = (const float*)d_in[22];
  const float* b2l_wv = (const float*)d_in[23]; const float* b2l_bv = (const float*)d_in[24];
  const float* b2l_wo = (const float*)d_in[25]; const float* b2l_bo = (const float*)d_in[26];
  const float* ff_w1  = (const float*)d_in[27]; const float* ff_b1  = (const float*)d_in[28];
  const float* ff_w2  = (const float*)d_in[29]; const float* ff_b2  = (const float*)d_in[30];
  const float* n1_g   = (const float*)d_in[31]; const float* n1_b   = (const float*)d_in[32];
  const float* n2_g   = (const float*)d_in[33]; const float* n2_b   = (const float*)d_in[34];

  char* ws = (char*)d_ws;
  size_t off = 0;
  auto alloc = [&](size_t bytes)->char*{ char* p = ws + off; off += (bytes + 255) & ~(size_t)255; return p; };
  u16*   wt     = (u16*)alloc(327680*2);
  u16*   q_sa   = (u16*)alloc(2097152);
  u16*   k_sa   = (u16*)alloc(2097152);
  u16*   vt_sa  = (u16*)alloc(2097152);
  u16*   q_l    = (u16*)alloc(1048576);
  u16*   k_l    = (u16*)alloc(1048576);
  u16*   vt_l   = (u16*)alloc(1048576);
  u16*   q_b    = (u16*)alloc(1048576);
  u16*   k_b    = (u16*)alloc(1048576);
  u16*   vt_b   = (u16*)alloc(1048576);
  u16*   ctx_sa = (u16*)alloc(2097152);
  u16*   ctx_l  = (u16*)alloc(1048576);
  u16*   ctx_b  = (u16*)alloc(1048576);
  u16*   xb     = (u16*)alloc(2097152);
  u16*   tbuf   = (u16*)alloc(8388608);
  u16*   hb     = tbuf;  // overlay: hb (2MB) dead before ff1 writes tbuf
  if (off > ws_size) return;  // workspace too small; fail validation visibly

  { WConvArgs a;
    const float* wlist[12] = {sa_wq,sa_wk,sa_wv,sa_wo,l2b_wq,l2b_wk,l2b_wv,l2b_wo,b2l_wq,b2l_wk,b2l_wv,b2l_wo};
    for (int i = 0; i < 12; ++i) a.w[i] = wlist[i];
    a.w1 = ff_w1; a.w2 = ff_w2; a.h = h; a.dst = wt; a.hb = hb;
    k_convert_w<<<1792, 256, 0, stream>>>(a);
  }

  const float QS = 0.25f * LOG2E;   // fold 1/sqrt(dh) and log2(e) into Q
  { ProjArgs a; a.X = hb;
    auto set = [&](int i, int widx, const float* bias, u16* dst, int lg, int offr, int vt, float sc, int end){
      a.d[i] = {wt + widx*16384, bias, dst, lg, offr, vt, end, sc}; };
    set(0, 0, sa_bq,  q_sa, 11,    0, 0, QS,    512);
    set(1, 1, sa_bk,  k_sa, 11,    0, 0, 1.f,  1024);
    set(2, 2, sa_bv, vt_sa, 11,    0, 1, 1.f,  1536);
    set(3, 4, l2b_bq,  q_l, 10,    0, 0, QS,   1792);
    set(4, 5, l2b_bk,  k_l, 10, 1024, 0, 1.f,  2048);
    set(5, 6, l2b_bv, vt_l, 10, 1024, 1, 1.f,  2304);
    set(6, 8, b2l_bq,  q_b, 10, 1024, 0, QS,   2560);
    set(7, 9, b2l_bk,  k_b, 10,    0, 0, 1.f,  2816);
    set(8,10, b2l_bv, vt_b, 10,    0, 1, 1.f,  3072);
    k_qkv<<<768, 256, 0, stream>>>(a);
  }

  { AttnArgs a;
    a.d[0] = {q_sa, k_sa, vt_sa, ctx_sa, 2048, 2048, 6, 2048};   // 32 bh x 64 q-tiles(32)
    a.d[1] = {q_l,  k_l,  vt_l,  ctx_l,  1024, 1024, 5, 3072};   // 32 bh x 32 q-tiles
    a.d[2] = {q_b,  k_b,  vt_b,  ctx_b,  1024, 1024, 5, 4096};
    k_attn<<<1024, 256, 0, stream>>>(a);
  }

  { OProjArgs a;
    a.ctx_sa = ctx_sa; a.ctx_l = ctx_l; a.ctx_b = ctx_b;
    a.wo_sa = wt + 3*16384; a.wo_l = wt + 7*16384; a.wo_b = wt + 11*16384;
    a.bo_sa = sa_bo; a.bo_l = l2b_bo; a.bo_b = b2l_bo;
    a.h = h; a.gam = n1_g; a.bet = n1_b; a.xb = xb;
    k_oproj<<<512, 64, 0, stream>>>(a);
  }

  k_ff1<<<512, 256, 0, stream>>>(xb, wt + 196608, ff_b1, tbuf);
  k_ff2ln<<<512, 64, 0, stream>>>(tbuf, wt + 262144, ff_b2, xb, n2_g, n2_b, (float*)d_out);
}

// Round 27
// 77.654 us; speedup vs baseline: 1.2002x; 1.2002x over previous
//
#include <hip/hip_runtime.h>

typedef unsigned short u16;
typedef short s16x4 __attribute__((ext_vector_type(4)));
typedef short short8 __attribute__((ext_vector_type(8)));
typedef __bf16 bf16x8 __attribute__((ext_vector_type(8)));
typedef float f32x4 __attribute__((ext_vector_type(4)));
typedef float f32x2 __attribute__((ext_vector_type(2)));
typedef float f32x16 __attribute__((ext_vector_type(16)));

#define DEV static __device__ __forceinline__

DEV u16 f2b(float f){
  union { float f; unsigned u; } v; v.f = f;
  return (u16)((v.u + 0x7fffu + ((v.u >> 16) & 1u)) >> 16);
}

DEV float b2f(u16 u){
  union { unsigned u; float f; } v; v.u = ((unsigned)u) << 16; return v.f;
}

DEV f32x4 mfma16(short8 a, short8 b, f32x4 c){
  return __builtin_amdgcn_mfma_f32_16x16x32_bf16(
      __builtin_bit_cast(bf16x8, a), __builtin_bit_cast(bf16x8, b), c, 0, 0, 0);
}

DEV f32x16 mfma32(short8 a, short8 b, f32x16 c){
  return __builtin_amdgcn_mfma_f32_32x32x16_bf16(
      __builtin_bit_cast(bf16x8, a), __builtin_bit_cast(bf16x8, b), c, 0, 0, 0);
}

DEV short8 ld8(const u16* p){ return *(const short8*)p; }

#if __has_builtin(__builtin_amdgcn_exp2f)
DEV float fexp2(float x){ return __builtin_amdgcn_exp2f(x); }
#else
DEV float fexp2(float x){ return exp2f(x); }
#endif

#define LOG2E 1.44269504088896341f

// ---------------- weight convert + transpose (fp32 -> bf16, [out_col][k]) + h -> bf16 (vec) -------
struct WConvArgs { const float* w[12]; const float* w1; const float* w2; const float* h; u16* dst; u16* hb; };
__global__ __launch_bounds__(256) void k_convert_w(WConvArgs a){
  int i = blockIdx.x*256 + threadIdx.x;
  if (i >= 458752) return;
  if (i >= 327680){
    int j = (i - 327680) << 3;          // 8 h elements per thread, coalesced
    f32x4 v0 = *(const f32x4*)(a.h + j);
    f32x4 v1 = *(const f32x4*)(a.h + j + 4);
    short8 o;
    #pragma unroll
    for (int t = 0; t < 4; ++t){ o[t] = (short)f2b(v0[t]); o[4+t] = (short)f2b(v1[t]); }
    *(short8*)(a.hb + j) = o;
    return;
  }
  float v;
  if (i < 196608){ int w = i >> 14, rem = i & 16383, c = rem >> 7, k = rem & 127; v = a.w[w][k*128 + c]; }
  else if (i < 262144){ int rem = i - 196608, c = rem >> 7, k = rem & 127; v = a.w1[k*512 + c]; }
  else { int rem = i - 262144, c = rem >> 9, k = rem & 511; v = a.w2[k*128 + c]; }
  a.dst[i] = f2b(v);
}

// ---------------- fused QKV projections (9 GEMMs, X = h bf16), 32x64 out per wave ----------------
// V output layout: [B, H, blk=N/32, dh=16, pos=32] with pos = key permuted (bits 2<->3 of krel)
// so attention's 32x32x16 PV A-fragment reads are contiguous 16B/lane.
struct ProjDesc {
  const u16* Wt; const float* bias; u16* dst;
  int lg_rpb, row_off, vtrans, tile_end; float scale;
};
struct ProjArgs { ProjDesc d[9]; const u16* X; };
__global__ __launch_bounds__(256) void k_qkv(ProjArgs A){
  int wave = (blockIdx.x << 2) + (threadIdx.x >> 6);
  int lane = threadIdx.x & 63;
  int j = 0, base = 0;
  #pragma unroll
  for (int t = 0; t < 8; ++t)
    if (wave >= A.d[t].tile_end){ j = t + 1; base = A.d[t].tile_end; }
  ProjDesc d = A.d[j];
  int local = wave - base;
  int ch = local & 1, rt = local >> 1;
  int lrow = lane & 15, lgrp = lane >> 4, kb = lgrp << 3;
  int rpb_m1 = (1 << d.lg_rpb) - 1;
  int nq = rpb_m1 + 1;
  int rA = (rt << 5) + lrow, rB = rA + 16;
  int gA = ((rA >> d.lg_rpb) << 11) + (rA & rpb_m1) + d.row_off;
  int gB = ((rB >> d.lg_rpb) << 11) + (rB & rpb_m1) + d.row_off;
  const u16* xpA = A.X + (size_t)gA*128 + kb;
  const u16* xpB = A.X + (size_t)gB*128 + kb;
  short8 aA0 = ld8(xpA), aA1 = ld8(xpA+32), aA2 = ld8(xpA+64), aA3 = ld8(xpA+96);
  short8 aB0 = ld8(xpB), aB1 = ld8(xpB+32), aB2 = ld8(xpB+64), aB3 = ld8(xpB+96);
  // constants for vtrans store
  int rr0base = rt << 5;
  int b_of = rr0base >> d.lg_rpb;            // block of 32 rows never crosses batch boundary
  int q0_ = rr0base & rpb_m1;
  int blk = q0_ >> 5;
  int lgrp2 = ((lgrp & 1) << 1) | (lgrp >> 1);   // swap the two bits (perm of key slots)
  #pragma unroll
  for (int cc = 0; cc < 4; ++cc){
    int c = (ch << 6) + (cc << 4) + lrow;
    const u16* wp = d.Wt + c*128 + kb;
    short8 w0 = ld8(wp), w1 = ld8(wp+32), w2 = ld8(wp+64), w3 = ld8(wp+96);
    f32x4 accA = {0.f,0.f,0.f,0.f}, accB = {0.f,0.f,0.f,0.f};
    accA = mfma16(aA0, w0, accA); accB = mfma16(aB0, w0, accB);
    accA = mfma16(aA1, w1, accA); accB = mfma16(aB1, w1, accB);
    accA = mfma16(aA2, w2, accA); accB = mfma16(aB2, w2, accB);
    accA = mfma16(aA3, w3, accA); accB = mfma16(aB3, w3, accB);
    float bv = d.bias[c];
    int hh = c >> 4, dd = c & 15;
    #pragma unroll
    for (int half = 0; half < 2; ++half){
      f32x4 acc = half ? accB : accA;
      if (d.vtrans){
        s16x4 ov;
        #pragma unroll
        for (int i = 0; i < 4; ++i) ov[i] = (short)f2b((acc[i] + bv) * d.scale);
        size_t off = ((size_t)((b_of*8 + hh)*(nq >> 5) + blk))*512 + dd*32 + half*16 + lgrp2*4;
        *(s16x4*)(d.dst + off) = ov;
      } else {
        #pragma unroll
        for (int i = 0; i < 4; ++i){
          int rr = (rt << 5) + half*16 + (lgrp << 2) + i;
          int b = rr >> d.lg_rpb, q = rr & rpb_m1;
          float val = (acc[i] + bv) * d.scale;
          size_t off = ((size_t)((b*8 + hh)*nq + q))*16 + dd;   // Q/K: [B,H,N,dh]
          d.dst[off] = f2b(val);
        }
      }
    }
  }
}

// ---------------- fused attention (3 attns, swapped-QK^T via 32x32x16, 32 q-rows/wave) ------
// 64 keys/iter as TWO independent 32-key chains (dual accumulators) for in-wave ILP.
// Per-wave STAGGERED key start (softmax sum is order-invariant); s_setprio(1) around MFMA.
// dh=16 == K of mfma_32x32x16. C/D layout: col=lane&31, row=(reg&3)+8*(reg>>2)+4*(lane>>5).
// V^T A-frag row 16 = ones -> PV row 16 = sum(P) = softmax denominator (free).
// Scores bounded (|s| << 1) -> no max subtraction. Q pre-scaled by 0.25*log2(e) -> exp2.
// XCD-aware block swizzle keeps each bh's K/V in one XCD's L2.
struct AttnDesc { const u16* Q; const u16* K; const u16* Vt; u16* ctx; int Nq, Nk, lg_nqt, wave_end; };
struct AttnArgs { AttnDesc d[3]; };
__global__ __launch_bounds__(256, 4) void k_attn(AttnArgs A){
  int wid = threadIdx.x >> 6, lane = threadIdx.x & 63;
  int p = blockIdx.x;
  int lb;
  if (p < 512){ lb = (p & 7)*64 + (p >> 3); }                       // sa: 8 xcd x 64 slots
  else if (p < 768){ int q = p - 512; lb = 512 + (q & 7)*32 + (q >> 3); }  // l2b
  else { int q = p - 768; lb = 768 + (q & 7)*32 + (q >> 3); }             // b2l
  int wave = (lb << 2) + wid;
  int j = 0, base = 0;
  #pragma unroll
  for (int t = 0; t < 2; ++t)
    if (wave >= A.d[t].wave_end){ j = t + 1; base = A.d[t].wave_end; }
  AttnDesc d = A.d[j];
  int local = wave - base;
  int bh = local >> d.lg_nqt;                  // lg_nqt = log2(#32-row q-tiles)
  int qt = local & ((1 << d.lg_nqt) - 1);
  int q0 = qt << 5;                            // 32 q-rows per wave
  int lq = lane & 31, hi = lane >> 5;
  const u16* Qb = d.Q + (size_t)bh * d.Nq * 16;
  const u16* Kb = d.K + (size_t)bh * d.Nk * 16;
  const u16* Vb = d.Vt + (size_t)bh * 16 * d.Nk;   // [blk][dh][pos32]
  short8 zs = {0,0,0,0,0,0,0,0};
  short8 ones = {0x3F80,0x3F80,0x3F80,0x3F80,0x3F80,0x3F80,0x3F80,0x3F80};
  short8 bq = ld8(Qb + (q0 + lq)*16 + hi*8);       // B-frag Q: col q=q0+lq
  const u16* kp0 = Kb + lq*16 + hi*8;              // A-frag K: row key=lq
  bool vload = lq < 16;
  bool vone  = lq == 16;
  const u16* vbase = Vb + (lq & 15)*32 + hi*8;
  f32x16 oA = {0.f,0.f,0.f,0.f,0.f,0.f,0.f,0.f,0.f,0.f,0.f,0.f,0.f,0.f,0.f,0.f};
  f32x16 oB = oA;
  f32x16 z16 = oA;
  int nt = d.Nk >> 6;                               // 64-key tiles (power of 2)
  int toff = wid * (nt >> 2);                       // stagger waves across key space
  for (int it = 0; it < nt; ++it){
    int k0 = ((it + toff) & (nt - 1)) << 6;
    short8 aK0 = ld8(kp0 + k0*16);
    short8 aK1 = ld8(kp0 + k0*16 + 512);
    short8 v0a, v1a, v0b, v1b;
    if (vload){
      const u16* vp = vbase + (size_t)(k0 >> 5)*512;
      v0a = ld8(vp);        v1a = ld8(vp + 16);
      v0b = ld8(vp + 512);  v1b = ld8(vp + 528);
    } else if (vone){ v0a = ones; v1a = ones; v0b = ones; v1b = ones; }
    else { v0a = zs; v1a = zs; v0b = zs; v1b = zs; }
    __builtin_amdgcn_s_setprio(1);
    f32x16 sA = mfma32(aK0, bq, z16);   // both QK MFMAs independent, issue back-to-back
    f32x16 sB = mfma32(aK1, bq, z16);
    __builtin_amdgcn_s_setprio(0);
    float pa[16], pb_[16];
    #pragma unroll
    for (int i = 0; i < 16; ++i){ pa[i] = fexp2(sA[i]); pb_[i] = fexp2(sB[i]); }
    bf16x8 a0, a1, b0, b1;
    #pragma unroll
    for (int i = 0; i < 8; ++i){
      a0[i] = (__bf16)pa[i]; a1[i] = (__bf16)pa[8+i];
      b0[i] = (__bf16)pb_[i]; b1[i] = (__bf16)pb_[8+i];
    }
    __builtin_amdgcn_s_setprio(1);
    oA = mfma32(v0a, __builtin_bit_cast(short8, a0), oA);
    oA = mfma32(v1a, __builtin_bit_cast(short8, a1), oA);
    oB = mfma32(v0b, __builtin_bit_cast(short8, b0), oB);
    oB = mfma32(v1b, __builtin_bit_cast(short8, b1), oB);
    __builtin_amdgcn_s_setprio(0);
  }
  f32x16 o = oA + oB;
  // denominator: D row 16 (reg 8, hi=0 lanes) = sum over all keys of P
  float l = o[8];
  l += __shfl_xor(l, 32);
  float invl = 1.f / l;
  int b = bh >> 3, h = bh & 7;
  u16* cb = d.ctx + ((size_t)(b*d.Nq + q0 + lq))*128 + h*16;
  s16x4 ov0, ov1;
  #pragma unroll
  for (int i = 0; i < 4; ++i){
    ov0[i] = (short)f2b(o[i]   * invl);       // regs 0-3: dv = i + 4*hi
    ov1[i] = (short)f2b(o[4+i] * invl);       // regs 4-7: dv = 8 + i + 4*hi
  }
  *(s16x4*)(cb + 4*hi)     = ov0;
  *(s16x4*)(cb + 8 + 4*hi) = ov1;
}

// ---------------- fused O projections + LN1: xb = bf16(LN1(h + ctx_sa@Wo_sa + ctx_het@Wo_het)) ----
// One wave per block (512 blocks -> 2 blocks/CU, all CUs busy), 16 rows x 128 cols, 64 MFMAs.
struct OProjArgs {
  const u16 *ctx_sa, *ctx_l, *ctx_b, *wo_sa, *wo_l, *wo_b;
  const float *bo_sa, *bo_l, *bo_b, *h, *gam, *bet;
  u16* xb;
};
__global__ __launch_bounds__(64) void k_oproj(OProjArgs A){
  int rt = blockIdx.x;                  // 512 blocks, 1 wave each
  int lane = threadIdx.x & 63;
  int lq = lane & 15, grp = lane >> 4, kb = grp << 3;
  int r0 = rt << 4;
  int r = r0 + lq;
  int b = r >> 11, q = r & 2047;
  bool lo = (q & 1024) == 0;
  int qh = q & 1023;
  const u16* asa = A.ctx_sa + (size_t)r*128 + kb;
  const u16* ah  = (lo ? A.ctx_l : A.ctx_b) + ((size_t)(b*1024 + qh))*128 + kb;
  short8 as0 = ld8(asa), as1 = ld8(asa+32), as2 = ld8(asa+64), as3 = ld8(asa+96);
  short8 ah0 = ld8(ah),  ah1 = ld8(ah+32),  ah2 = ld8(ah+64),  ah3 = ld8(ah+96);
  const u16* wlo = lo ? A.wo_l : A.wo_b;
  const float* blo = lo ? A.bo_l : A.bo_b;
  float v[8][4];                        // v[ct][i]: row r0+grp*4+i, col ct*16+lq
  #pragma unroll
  for (int ct = 0; ct < 8; ++ct){
    int c = (ct << 4) + lq;
    const u16* wsa = A.wo_sa + c*128 + kb;
    const u16* wh  = wlo + c*128 + kb;
    f32x4 acc = {0.f,0.f,0.f,0.f};
    acc = mfma16(as0, ld8(wsa),      acc);
    acc = mfma16(as1, ld8(wsa + 32), acc);
    acc = mfma16(as2, ld8(wsa + 64), acc);
    acc = mfma16(as3, ld8(wsa + 96), acc);
    acc = mfma16(ah0, ld8(wh),       acc);
    acc = mfma16(ah1, ld8(wh + 32),  acc);
    acc = mfma16(ah2, ld8(wh + 64),  acc);
    acc = mfma16(ah3, ld8(wh + 96),  acc);
    float bv = A.bo_sa[c] + blo[c];
    #pragma unroll
    for (int i = 0; i < 4; ++i){
      int rr = r0 + (grp << 2) + i;
      v[ct][i] = A.h[(size_t)rr*128 + c] + acc[i] + bv;
    }
  }
  // per-row LN over the 16 lanes of this group
  float s[4], sq[4];
  #pragma unroll
  for (int i = 0; i < 4; ++i){
    float a = 0.f, bb = 0.f;
    #pragma unroll
    for (int ct = 0; ct < 8; ++ct){ a += v[ct][i]; bb += v[ct][i]*v[ct][i]; }
    s[i] = a; sq[i] = bb;
  }
  #pragma unroll
  for (int dd = 1; dd < 16; dd <<= 1){
    #pragma unroll
    for (int i = 0; i < 4; ++i){ s[i] += __shfl_xor(s[i], dd); sq[i] += __shfl_xor(sq[i], dd); }
  }
  float mean[4], rstd[4];
  #pragma unroll
  for (int i = 0; i < 4; ++i){
    mean[i] = s[i] * 0.0078125f;
    rstd[i] = rsqrtf(fmaxf(sq[i]*0.0078125f - mean[i]*mean[i], 0.f) + 1e-5f);
  }
  #pragma unroll
  for (int ct = 0; ct < 8; ++ct){
    int c = (ct << 4) + lq;
    float g = A.gam[c], be = A.bet[c];
    #pragma unroll
    for (int i = 0; i < 4; ++i){
      int rr = r0 + (grp << 2) + i;
      A.xb[(size_t)rr*128 + c] = f2b((v[ct][i] - mean[i])*rstd[i]*g + be);
    }
  }
}

// ---------------- FF1 (pure GEMM): t = relu(xb @ W1 + b1), 32 rows x 64 cols per wave ----------
__global__ __launch_bounds__(256) void k_ff1(const u16* xb, const u16* w1t, const float* b1, u16* t){
  int wave = (blockIdx.x << 2) + (threadIdx.x >> 6);
  int lane = threadIdx.x & 63;
  int ch = wave & 7, rt = wave >> 3;
  int lrow = lane & 15, lgrp = lane >> 4, kb = lgrp << 3;
  int rA = (rt << 5) + lrow, rB = rA + 16;
  const u16* xpA = xb + (size_t)rA*128 + kb;
  const u16* xpB = xb + (size_t)rB*128 + kb;
  short8 aA0 = ld8(xpA), aA1 = ld8(xpA+32), aA2 = ld8(xpA+64), aA3 = ld8(xpA+96);
  short8 aB0 = ld8(xpB), aB1 = ld8(xpB+32), aB2 = ld8(xpB+64), aB3 = ld8(xpB+96);
  #pragma unroll
  for (int cc = 0; cc < 4; ++cc){
    int c = (ch << 6) + (cc << 4) + lrow;
    const u16* wp = w1t + c*128 + kb;
    short8 w0 = ld8(wp), w1 = ld8(wp+32), w2 = ld8(wp+64), w3 = ld8(wp+96);
    f32x4 accA = {0.f,0.f,0.f,0.f}, accB = {0.f,0.f,0.f,0.f};
    accA = mfma16(aA0, w0, accA); accB = mfma16(aB0, w0, accB);
    accA = mfma16(aA1, w1, accA); accB = mfma16(aB1, w1, accB);
    accA = mfma16(aA2, w2, accA); accB = mfma16(aB2, w2, accB);
    accA = mfma16(aA3, w3, accA); accB = mfma16(aB3, w3, accB);
    float bv = b1[c];
    #pragma unroll
    for (int half = 0; half < 2; ++half){
      f32x4 acc = half ? accB : accA;
      #pragma unroll
      for (int i = 0; i < 4; ++i){
        int rr = (rt << 5) + half*16 + (lgrp << 2) + i;
        t[(size_t)rr*512 + c] = f2b(fmaxf(acc[i] + bv, 0.f));
      }
    }
  }
}

// ---------------- FF2 + final LN fused: out = LN(xb + t @ W2 + b2)  ----------------
// One wave per 16 rows, full 128 cols (8 col-tiles, K=512 -> 128 MFMAs).
// After epilogue each 16-lane group holds complete rows -> in-register LN, write d_out.
__global__ __launch_bounds__(64) void k_ff2ln(const u16* t, const u16* w2t, const float* b2,
                                              const u16* xb, const float* gam, const float* bet,
                                              float* out){
  int rt = blockIdx.x;                 // 512 blocks, 1 wave each
  int lane = threadIdx.x & 63;
  int lq = lane & 15, grp = lane >> 4, kb = grp << 3;
  int r0 = rt << 4;
  const u16* ap = t + (size_t)(r0 + lq)*512 + kb;
  short8 af[16];
  #pragma unroll
  for (int ks = 0; ks < 16; ++ks) af[ks] = ld8(ap + ks*32);
  float v[8][4];                       // v[ct][i]: row r0+grp*4+i, col ct*16+lq
  #pragma unroll
  for (int ct = 0; ct < 8; ++ct){
    int c = (ct << 4) + lq;
    const u16* wp = w2t + (size_t)c*512 + kb;
    f32x4 acc = {0.f,0.f,0.f,0.f};
    #pragma unroll
    for (int ks = 0; ks < 16; ++ks) acc = mfma16(af[ks], ld8(wp + ks*32), acc);
    float bv = b2[c];
    #pragma unroll
    for (int i = 0; i < 4; ++i){
      int rr = r0 + (grp << 2) + i;
      v[ct][i] = b2f(xb[(size_t)rr*128 + c]) + acc[i] + bv;
    }
  }
  // per-row LN: row rr held by the 16 lanes of this grp (8 cols each)
  float s[4], sq[4];
  #pragma unroll
  for (int i = 0; i < 4; ++i){
    float a = 0.f, b = 0.f;
    #pragma unroll
    for (int ct = 0; ct < 8; ++ct){ a += v[ct][i]; b += v[ct][i]*v[ct][i]; }
    s[i] = a; sq[i] = b;
  }
  #pragma unroll
  for (int d = 1; d < 16; d <<= 1){
    #pragma unroll
    for (int i = 0; i < 4; ++i){ s[i] += __shfl_xor(s[i], d); sq[i] += __shfl_xor(sq[i], d); }
  }
  float mean[4], rstd[4];
  #pragma unroll
  for (int i = 0; i < 4; ++i){
    mean[i] = s[i] * 0.0078125f;
    rstd[i] = rsqrtf(fmaxf(sq[i]*0.0078125f - mean[i]*mean[i], 0.f) + 1e-5f);
  }
  #pragma unroll
  for (int ct = 0; ct < 8; ++ct){
    int c = (ct << 4) + lq;
    float g = gam[c], be = bet[c];
    #pragma unroll
    for (int i = 0; i < 4; ++i){
      int rr = r0 + (grp << 2) + i;
      out[(size_t)rr*128 + c] = (v[ct][i] - mean[i])*rstd[i]*g + be;
    }
  }
}

extern "C" void kernel_launch(void* const* d_in, const int* in_sizes, int n_in,
                              void* d_out, int out_size, void* d_ws, size_t ws_size,
                              hipStream_t stream){
  const float* h      = (const float*)d_in[0];
  const float* sa_wq  = (const float*)d_in[3];  const float* sa_bq  = (const float*)d_in[4];
  const float* sa_wk  = (const float*)d_in[5];  const float* sa_bk  = (const float*)d_in[6];
  const float* sa_wv  = (const float*)d_in[7];  const float* sa_bv  = (const float*)d_in[8];
  const float* sa_wo  = (const float*)d_in[9];  const float* sa_bo  = (const float*)d_in[10];
  const float* l2b_wq = (const float*)d_in[11]; const float* l2b_bq = (const float*)d_in[12];
  const float* l2b_wk = (const float*)d_in[13]; const float* l2b_bk = (const float*)d_in[14];
  const float* l2b_wv = (const float*)d_in[15]; const float* l2b_bv = (const float*)d_in[16];
  const float* l2b_wo = (const float*)d_in[17]; const float* l2b_bo = (const float*)d_in[18];
  const float* b2l_wq = (const float*)d_in[19]; const float* b2l_bq = (const float*)d_in[20];
  const float* b2l_wk = (const float*)d_in[21]; const float* b2l_bk = (const float*)d_in[22];
  const float* b2l_wv = (const float*)d_in[23]; const float* b2l_bv = (const float*)d_in[24];
  const float* b2l_wo = (const float*)d_in[25]; const float* b2l_bo = (const float*)d_in[26];
  const float* ff_w1  = (const float*)d_in[27]; const float* ff_b1  = (const float*)d_in[28];
  const float* ff_w2  = (const float*)d_in[29]; const float* ff_b2  = (const float*)d_in[30];
  const float* n1_g   = (const float*)d_in[31]; const float* n1_b   = (const float*)d_in[32];
  const float* n2_g   = (const float*)d_in[33]; const float* n2_b   = (const float*)d_in[34];

  char* ws = (char*)d_ws;
  size_t off = 0;
  auto alloc = [&](size_t bytes)->char*{ char* p = ws + off; off += (bytes + 255) & ~(size_t)255; return p; };
  u16*   wt     = (u16*)alloc(327680*2);
  u16*   q_sa   = (u16*)alloc(2097152);
  u16*   k_sa   = (u16*)alloc(2097152);
  u16*   vt_sa  = (u16*)alloc(2097152);
  u16*   q_l    = (u16*)alloc(1048576);
  u16*   k_l    = (u16*)alloc(1048576);
  u16*   vt_l   = (u16*)alloc(1048576);
  u16*   q_b    = (u16*)alloc(1048576);
  u16*   k_b    = (u16*)alloc(1048576);
  u16*   vt_b   = (u16*)alloc(1048576);
  u16*   ctx_sa = (u16*)alloc(2097152);
  u16*   ctx_l  = (u16*)alloc(1048576);
  u16*   ctx_b  = (u16*)alloc(1048576);
  u16*   xb     = (u16*)alloc(2097152);
  u16*   tbuf   = (u16*)alloc(8388608);
  u16*   hb     = tbuf;  // overlay: hb (2MB) dead before ff1 writes tbuf
  if (off > ws_size) return;  // workspace too small; fail validation visibly

  { WConvArgs a;
    const float* wlist[12] = {sa_wq,sa_wk,sa_wv,sa_wo,l2b_wq,l2b_wk,l2b_wv,l2b_wo,b2l_wq,b2l_wk,b2l_wv,b2l_wo};
    for (int i = 0; i < 12; ++i) a.w[i] = wlist[i];
    a.w1 = ff_w1; a.w2 = ff_w2; a.h = h; a.dst = wt; a.hb = hb;
    k_convert_w<<<1792, 256, 0, stream>>>(a);
  }

  const float QS = 0.25f * LOG2E;   // fold 1/sqrt(dh) and log2(e) into Q
  { ProjArgs a; a.X = hb;
    auto set = [&](int i, int widx, const float* bias, u16* dst, int lg, int offr, int vt, float sc, int end){
      a.d[i] = {wt + widx*16384, bias, dst, lg, offr, vt, end, sc}; };
    set(0, 0, sa_bq,  q_sa, 11,    0, 0, QS,    512);
    set(1, 1, sa_bk,  k_sa, 11,    0, 0, 1.f,  1024);
    set(2, 2, sa_bv, vt_sa, 11,    0, 1, 1.f,  1536);
    set(3, 4, l2b_bq,  q_l, 10,    0, 0, QS,   1792);
    set(4, 5, l2b_bk,  k_l, 10, 1024, 0, 1.f,  2048);
    set(5, 6, l2b_bv, vt_l, 10, 1024, 1, 1.f,  2304);
    set(6, 8, b2l_bq,  q_b, 10, 1024, 0, QS,   2560);
    set(7, 9, b2l_bk,  k_b, 10,    0, 0, 1.f,  2816);
    set(8,10, b2l_bv, vt_b, 10,    0, 1, 1.f,  3072);
    k_qkv<<<768, 256, 0, stream>>>(a);
  }

  { AttnArgs a;
    a.d[0] = {q_sa, k_sa, vt_sa, ctx_sa, 2048, 2048, 6, 2048};   // 32 bh x 64 q-tiles(32)
    a.d[1] = {q_l,  k_l,  vt_l,  ctx_l,  1024, 1024, 5, 3072};   // 32 bh x 32 q-tiles
    a.d[2] = {q_b,  k_b,  vt_b,  ctx_b,  1024, 1024, 5, 4096};
    k_attn<<<1024, 256, 0, stream>>>(a);
  }

  { OProjArgs a;
    a.ctx_sa = ctx_sa; a.ctx_l = ctx_l; a.ctx_b = ctx_b;
    a.wo_sa = wt + 3*16384; a.wo_l = wt + 7*16384; a.wo_b = wt + 11*16384;
    a.bo_sa = sa_bo; a.bo_l = l2b_bo; a.bo_b = b2l_bo;
    a.h = h; a.gam = n1_g; a.bet = n1_b; a.xb = xb;
    k_oproj<<<512, 64, 0, stream>>>(a);
  }

  k_ff1<<<512, 256, 0, stream>>>(xb, wt + 196608, ff_b1, tbuf);
  k_ff2ln<<<512, 64, 0, stream>>>(tbuf, wt + 262144, ff_b2, xb, n2_g, n2_b, (float*)d_out);
}